// Round 4
// baseline (172.934 us; speedup 1.0000x reference)
//
#include <hip/hip_runtime.h>
#include <cstdint>
#include <cstddef>

#define T_TOK 8192
#define H_DIM 512
#define E_NUM 16
#define F_DIM 1024

typedef __bf16 bf16x8 __attribute__((ext_vector_type(8)));
typedef float f32x4 __attribute__((ext_vector_type(4)));

// ws layout (bytes) — total ~92.6 MB
#define OFF_XBF  0UL          // 8192*512*2            = 8,388,608
#define OFF_HID  8388608UL    // 16384*1024*2          = 33,554,432
#define OFF_GW   41943040UL   // 16 MB bf16 tiled gate
#define OFF_UW   58720256UL   // 16 MB bf16 tiled up
#define OFF_DW   75497472UL   // 16 MB bf16 tiled down
#define OFF_STOK 92274688UL
#define OFF_SW   92340224UL
#define OFF_TOPE 92405760UL
#define OFF_TOPW 92471296UL
#define OFF_CNT  92536832UL
#define OFF_CUR  92537856UL
#define OFF_OFFS 92538880UL

__device__ __forceinline__ unsigned short f2bf(float f) {
  union { float f; uint32_t u; } v; v.f = f;
  uint32_t r = v.u + 0x7fffu + ((v.u >> 16) & 1u);
  return (unsigned short)(r >> 16);
}

__device__ __forceinline__ void gld16(const void* g, void* l) {
  __builtin_amdgcn_global_load_lds(
      (const __attribute__((address_space(1))) unsigned int*)g,
      (__attribute__((address_space(3))) unsigned int*)l, 16, 0, 0);
}

// ---------------- fused pre-pass: weight prep (gu, dw) + router ----------------
// bid [0,4096):    gate/up fp32->bf16 tiling (XOR-swizzled LDS images)
// bid [4096,5120): down    fp32->bf16 tiling
// bid [5120,7168): router (wave per token) + x->bf16
__global__ __launch_bounds__(256) void k_pre(
    const float* __restrict__ x, const float* __restrict__ rw,
    const float* __restrict__ gw, const float* __restrict__ uw,
    const float* __restrict__ dw,
    unsigned short* __restrict__ xbf, int* __restrict__ tope,
    float* __restrict__ topw,
    unsigned short* __restrict__ gws, unsigned short* __restrict__ uws,
    unsigned short* __restrict__ dws) {
  const int bid = blockIdx.x;
  const int tid = threadIdx.x;
  __shared__ float ls[32 * 260];

  if (bid < 4096) {
    // ---- gate/up prep: tiles [e][ftile=8][kchunk=16] of [128 f][4 slots of 16B]
    const int fx = bid & 7, kc = (bid >> 3) & 15, ez = bid >> 7;
    const int e = ez >> 1;
    const float* src = ((ez & 1) ? uw : gw) + (size_t)e * H_DIM * F_DIM;
    unsigned short* dst = ((ez & 1) ? uws : gws);
    #pragma unroll
    for (int j = 0; j < 4; ++j) {
      int vi = tid + j * 256;
      int row = vi >> 5, c4 = (vi & 31) * 4;
      float4 v = *(const float4*)&src[(size_t)(kc*32 + row) * F_DIM + fx*128 + c4];
      ls[row*132 + c4+0]=v.x; ls[row*132 + c4+1]=v.y;
      ls[row*132 + c4+2]=v.z; ls[row*132 + c4+3]=v.w;
    }
    __syncthreads();
    size_t obase = (((size_t)e * 8 + fx) * 16 + kc) * 4096;  // ushorts
    #pragma unroll
    for (int j = 0; j < 2; ++j) {
      int oi = tid + j * 256;
      int f = oi >> 2, slot = oi & 3;
      int ks = ((slot ^ f) & 3) * 8;
      uint4 o;
      o.x = (uint32_t)f2bf(ls[(ks+0)*132 + f]) | ((uint32_t)f2bf(ls[(ks+1)*132 + f]) << 16);
      o.y = (uint32_t)f2bf(ls[(ks+2)*132 + f]) | ((uint32_t)f2bf(ls[(ks+3)*132 + f]) << 16);
      o.z = (uint32_t)f2bf(ls[(ks+4)*132 + f]) | ((uint32_t)f2bf(ls[(ks+5)*132 + f]) << 16);
      o.w = (uint32_t)f2bf(ls[(ks+6)*132 + f]) | ((uint32_t)f2bf(ls[(ks+7)*132 + f]) << 16);
      *(uint4*)&dst[obase + (size_t)oi * 8] = o;
    }
  } else if (bid < 5120) {
    // ---- down prep: tiles [e][htile=2][kchunk=32] of [256 h][4 slots]
    const int i = bid - 4096;
    const int ht = i & 1, kc = (i >> 1) & 31, e = i >> 6;
    const float* src = dw + (size_t)e * F_DIM * H_DIM;
    #pragma unroll
    for (int j = 0; j < 8; ++j) {
      int vi = tid + j * 256;
      int row = vi >> 6, c4 = (vi & 63) * 4;
      float4 v = *(const float4*)&src[(size_t)(kc*32 + row) * H_DIM + ht*256 + c4];
      ls[row*260 + c4+0]=v.x; ls[row*260 + c4+1]=v.y;
      ls[row*260 + c4+2]=v.z; ls[row*260 + c4+3]=v.w;
    }
    __syncthreads();
    size_t obase = (((size_t)e * 2 + ht) * 32 + kc) * 8192;  // ushorts
    #pragma unroll
    for (int j = 0; j < 4; ++j) {
      int oi = tid + j * 256;
      int h = oi >> 2, slot = oi & 3;
      int ks = ((slot ^ h) & 3) * 8;
      uint4 o;
      o.x = (uint32_t)f2bf(ls[(ks+0)*260 + h]) | ((uint32_t)f2bf(ls[(ks+1)*260 + h]) << 16);
      o.y = (uint32_t)f2bf(ls[(ks+2)*260 + h]) | ((uint32_t)f2bf(ls[(ks+3)*260 + h]) << 16);
      o.z = (uint32_t)f2bf(ls[(ks+4)*260 + h]) | ((uint32_t)f2bf(ls[(ks+5)*260 + h]) << 16);
      o.w = (uint32_t)f2bf(ls[(ks+6)*260 + h]) | ((uint32_t)f2bf(ls[(ks+7)*260 + h]) << 16);
      *(uint4*)&dws[obase + (size_t)oi * 8] = o;
    }
  } else {
    // ---- router: wave per token
    const int rb = bid - 5120;
    const int wave = tid >> 6, lane = tid & 63;
    const int t = rb * 4 + wave;
    const float4* xr = (const float4*)(x + (size_t)t * H_DIM + lane * 8);
    float4 a = xr[0], b = xr[1];
    float xi[8] = {a.x, a.y, a.z, a.w, b.x, b.y, b.z, b.w};
    uint4 o;
    o.x = (uint32_t)f2bf(xi[0]) | ((uint32_t)f2bf(xi[1]) << 16);
    o.y = (uint32_t)f2bf(xi[2]) | ((uint32_t)f2bf(xi[3]) << 16);
    o.z = (uint32_t)f2bf(xi[4]) | ((uint32_t)f2bf(xi[5]) << 16);
    o.w = (uint32_t)f2bf(xi[6]) | ((uint32_t)f2bf(xi[7]) << 16);
    *(uint4*)(xbf + (size_t)t * H_DIM + lane * 8) = o;
    float acc[E_NUM];
    #pragma unroll
    for (int e = 0; e < E_NUM; ++e) {
      const float4* wr = (const float4*)(rw + e * H_DIM + lane * 8);
      float4 wa = wr[0], wb = wr[1];
      acc[e] = xi[0]*wa.x + xi[1]*wa.y + xi[2]*wa.z + xi[3]*wa.w
             + xi[4]*wb.x + xi[5]*wb.y + xi[6]*wb.z + xi[7]*wb.w;
    }
    #pragma unroll
    for (int off = 1; off < 64; off <<= 1) {
      #pragma unroll
      for (int e = 0; e < E_NUM; ++e) acc[e] += __shfl_xor(acc[e], off);
    }
    if (lane == 0) {
      int e0 = 0; float v0 = acc[0];
      #pragma unroll
      for (int e = 1; e < E_NUM; ++e) if (acc[e] > v0) { v0 = acc[e]; e0 = e; }
      int e1 = -1; float v1 = -3.4e38f;
      #pragma unroll
      for (int e = 0; e < E_NUM; ++e) if (e != e0 && acc[e] > v1) { v1 = acc[e]; e1 = e; }
      float ee = __expf(v1 - v0);
      float inv = 1.0f / (1.0f + ee);
      tope[t*2]   = e0; tope[t*2+1] = e1;
      topw[t*2]   = inv; topw[t*2+1] = ee * inv;
    }
  }
}

__global__ __launch_bounds__(256) void k_hist(
    const int* __restrict__ tope, int* __restrict__ counts) {
  __shared__ int lh[E_NUM];
  const int tid = threadIdx.x;
  if (tid < E_NUM) lh[tid] = 0;
  __syncthreads();
  atomicAdd(&lh[tope[blockIdx.x * 256 + tid]], 1);
  __syncthreads();
  if (tid < E_NUM) atomicAdd(&counts[tid * 16], lh[tid]);
}

__global__ void k_offsets(const int* __restrict__ counts, int* __restrict__ offs) {
  if (threadIdx.x == 0 && blockIdx.x == 0) {
    int s = 0;
    for (int e = 0; e < E_NUM; ++e) { offs[e] = s; s += counts[e * 16]; }
    offs[E_NUM] = s;
  }
}

__global__ __launch_bounds__(256) void k_scatter(
    const int* __restrict__ tope, const float* __restrict__ topw,
    const int* __restrict__ offs, int* __restrict__ cursors,
    int* __restrict__ stok, float* __restrict__ sw) {
  __shared__ int lh[E_NUM];
  __shared__ int lbase[E_NUM];
  const int tid = threadIdx.x;
  const int t = blockIdx.x * 256 + tid;
  if (tid < E_NUM) lh[tid] = 0;
  __syncthreads();
  int e0 = tope[t*2], e1 = tope[t*2+1];
  int r0 = atomicAdd(&lh[e0], 1);
  int r1 = atomicAdd(&lh[e1], 1);
  __syncthreads();
  if (tid < E_NUM) lbase[tid] = atomicAdd(&cursors[tid * 16], lh[tid]);
  __syncthreads();
  int s0 = offs[e0] + lbase[e0] + r0;
  int s1 = offs[e1] + lbase[e1] + r1;
  stok[s0] = t; sw[s0] = topw[t*2];
  stok[s1] = t; sw[s1] = topw[t*2+1];
}

// ---------------- gate/up GEMM + SiLU ----------------
// block: 128 tokens x 128 f, 4 waves (2x2), BK=32, 16 chunks, global_load_lds + swizzle
__global__ __launch_bounds__(256, 2) void k_gateup(
    const unsigned short* __restrict__ xbf,
    const unsigned short* __restrict__ gws, const unsigned short* __restrict__ uws,
    const int* __restrict__ stok, const int* __restrict__ counts,
    const int* __restrict__ offs, unsigned short* __restrict__ hid) {
  const int e = blockIdx.z;
  const int cnt = counts[e * 16];
  const int t0 = blockIdx.y * 128;
  if (t0 >= cnt) return;
  const int base = offs[e];
  const int fx = blockIdx.x;

  __shared__ __align__(16) unsigned short sb[2][3][4096];  // A,G,U  48 KB

  const int tid = threadIdx.x;
  const int wave = tid >> 6, lane = tid & 63;
  const int l15 = lane & 15, hi = lane >> 4;
  const int wm = wave >> 1, wn = wave & 1;

  const int r0 = tid >> 2, slot = tid & 3;
  const int rr0 = min(t0 + r0, cnt - 1), rr1 = min(t0 + r0 + 64, cnt - 1);
  const char* sA0 = (const char*)xbf + (size_t)stok[base + rr0] * 1024 + ((slot ^ (r0 & 3)) * 16);
  const char* sA1 = (const char*)xbf + (size_t)stok[base + rr1] * 1024 + ((slot ^ (r0 & 3)) * 16);
  const char* sG = (const char*)gws + (((size_t)e * 8 + fx) * 16) * 8192 + tid * 16;
  const char* sU = (const char*)uws + (((size_t)e * 8 + fx) * 16) * 8192 + tid * 16;
  unsigned short* const dA = &sb[0][0][wave * 512];
  unsigned short* const dG = &sb[0][1][wave * 512];
  unsigned short* const dU = &sb[0][2][wave * 512];
  const int bufo = 3 * 4096;  // ushort stride between buffers

  f32x4 accg[4][4] = {}; f32x4 accu[4][4] = {};

  #define STAGE_GU(b, kk) { \
    gld16(sA0 + (kk)*64, dA + (b)*bufo); \
    gld16(sA1 + (kk)*64, dA + (b)*bufo + 2048); \
    gld16(sG + (size_t)(kk)*8192, dG + (b)*bufo); \
    gld16(sG + (size_t)(kk)*8192 + 4096, dG + (b)*bufo + 2048); \
    gld16(sU + (size_t)(kk)*8192, dU + (b)*bufo); \
    gld16(sU + (size_t)(kk)*8192 + 4096, dU + (b)*bufo + 2048); }

  STAGE_GU(0, 0);
  __syncthreads();
  #pragma unroll 1
  for (int kk = 0; kk < 16; ++kk) {
    const int cur = kk & 1;
    if (kk < 15) STAGE_GU(cur ^ 1, kk + 1);
    const unsigned short* lA = &sb[cur][0][0];
    const unsigned short* lG = &sb[cur][1][0];
    const unsigned short* lU = &sb[cur][2][0];
    bf16x8 a[4], bg[4], bu[4];
    #pragma unroll
    for (int m = 0; m < 4; ++m) {
      int row = wm*64 + m*16 + l15;
      a[m] = *(const bf16x8*)((const char*)lA + row*64 + (((hi ^ row) & 3) << 4));
    }
    #pragma unroll
    for (int s = 0; s < 4; ++s) {
      int row = wn*64 + s*16 + l15;
      int o = row*64 + (((hi ^ row) & 3) << 4);
      bg[s] = *(const bf16x8*)((const char*)lG + o);
      bu[s] = *(const bf16x8*)((const char*)lU + o);
    }
    #pragma unroll
    for (int m = 0; m < 4; ++m)
      #pragma unroll
      for (int s = 0; s < 4; ++s) {
        accg[m][s] = __builtin_amdgcn_mfma_f32_16x16x32_bf16(a[m], bg[s], accg[m][s], 0, 0, 0);
        accu[m][s] = __builtin_amdgcn_mfma_f32_16x16x32_bf16(a[m], bu[s], accu[m][s], 0, 0, 0);
      }
    __syncthreads();
  }
  #undef STAGE_GU

  #pragma unroll
  for (int m = 0; m < 4; ++m)
    #pragma unroll
    for (int r = 0; r < 4; ++r) {
      int row = t0 + wm*64 + m*16 + hi*4 + r;
      if (row < cnt) {
        #pragma unroll
        for (int s = 0; s < 4; ++s) {
          float g = accg[m][s][r], u = accu[m][s][r];
          float h = g / (1.0f + __expf(-g)) * u;
          hid[(size_t)(base + row) * 1024 + fx*128 + wn*64 + s*16 + l15] = f2bf(h);
        }
      }
    }
}

// ---------------- down GEMM + weighted scatter ----------------
// block: 64 tokens x 256 h, 4 waves (1m x 4n, wave = 64t x 64h), BK=32, 32 chunks
// 64-token tiles -> ~512 real blocks (2/CU) vs 256 at 128-token tiles: occupancy fix
__global__ __launch_bounds__(256, 3) void k_down(
    const unsigned short* __restrict__ hid, const unsigned short* __restrict__ dws,
    const int* __restrict__ stok, const float* __restrict__ sw,
    const int* __restrict__ counts, const int* __restrict__ offs,
    float* __restrict__ out) {
  const int e = blockIdx.z;
  const int cnt = counts[e * 16];
  const int t0 = blockIdx.y * 64;
  if (t0 >= cnt) return;
  const int base = offs[e];
  const int ht = blockIdx.x;

  __shared__ __align__(16) unsigned short sbA[2][2048];   // 8 KB
  __shared__ __align__(16) unsigned short sbW[2][8192];   // 32 KB

  const int tid = threadIdx.x;
  const int wave = tid >> 6, lane = tid & 63;
  const int l15 = lane & 15, hi = lane >> 4;

  const int r0 = tid >> 2, slot = tid & 3;
  const int rr = min(t0 + r0, cnt - 1);
  const char* sA = (const char*)hid + (size_t)(base + rr) * 2048 + ((slot ^ (r0 & 3)) * 16);
  const char* sW = (const char*)dws + (((size_t)e * 2 + ht) * 32) * 16384 + tid * 16;
  unsigned short* const dA = &sbA[0][wave * 512];
  unsigned short* const dW = &sbW[0][wave * 512];

  f32x4 acc[4][4] = {};

  #define STAGE_DN(b, kk) { \
    gld16(sA + (kk)*64, dA + (b)*2048); \
    const char* w = sW + (size_t)(kk)*16384; \
    gld16(w,         dW + (b)*8192); \
    gld16(w + 4096,  dW + (b)*8192 + 2048); \
    gld16(w + 8192,  dW + (b)*8192 + 4096); \
    gld16(w + 12288, dW + (b)*8192 + 6144); }

  STAGE_DN(0, 0);
  __syncthreads();
  #pragma unroll 1
  for (int kk = 0; kk < 32; ++kk) {
    const int cur = kk & 1;
    if (kk < 31) STAGE_DN(cur ^ 1, kk + 1);
    const unsigned short* lA = &sbA[cur][0];
    const unsigned short* lW = &sbW[cur][0];
    bf16x8 a[4], b[4];
    #pragma unroll
    for (int m = 0; m < 4; ++m) {
      int row = m*16 + l15;
      a[m] = *(const bf16x8*)((const char*)lA + row*64 + (((hi ^ row) & 3) << 4));
    }
    #pragma unroll
    for (int s = 0; s < 4; ++s) {
      int row = wave*64 + s*16 + l15;
      b[s] = *(const bf16x8*)((const char*)lW + row*64 + (((hi ^ row) & 3) << 4));
    }
    #pragma unroll
    for (int m = 0; m < 4; ++m)
      #pragma unroll
      for (int s = 0; s < 4; ++s)
        acc[m][s] = __builtin_amdgcn_mfma_f32_16x16x32_bf16(a[m], b[s], acc[m][s], 0, 0, 0);
    __syncthreads();
  }
  #undef STAGE_DN

  #pragma unroll
  for (int m = 0; m < 4; ++m)
    #pragma unroll
    for (int r = 0; r < 4; ++r) {
      int row = t0 + m*16 + hi*4 + r;
      if (row < cnt) {
        int sl = base + row;
        int t = stok[sl];
        float w = sw[sl];
        float* orow = out + (size_t)t * H_DIM + ht*256 + wave*64;
        #pragma unroll
        for (int s = 0; s < 4; ++s)
          atomicAdd(&orow[s*16 + l15], w * acc[m][s][r]);
      }
    }
}

extern "C" void kernel_launch(void* const* d_in, const int* in_sizes, int n_in,
                              void* d_out, int out_size, void* d_ws, size_t ws_size,
                              hipStream_t stream) {
  const float* x  = (const float*)d_in[0];
  const float* rw = (const float*)d_in[1];
  const float* gw = (const float*)d_in[2];
  const float* uw = (const float*)d_in[3];
  const float* dw = (const float*)d_in[4];
  float* out = (float*)d_out;
  char* ws = (char*)d_ws;

  unsigned short* xbf = (unsigned short*)(ws + OFF_XBF);
  unsigned short* hid = (unsigned short*)(ws + OFF_HID);
  unsigned short* gws = (unsigned short*)(ws + OFF_GW);
  unsigned short* uws = (unsigned short*)(ws + OFF_UW);
  unsigned short* dws = (unsigned short*)(ws + OFF_DW);
  int*   stok    = (int*)(ws + OFF_STOK);
  float* swt     = (float*)(ws + OFF_SW);
  int*   tope    = (int*)(ws + OFF_TOPE);
  float* topw    = (float*)(ws + OFF_TOPW);
  int*   counts  = (int*)(ws + OFF_CNT);
  int*   cursors = (int*)(ws + OFF_CUR);
  int*   offs    = (int*)(ws + OFF_OFFS);

  hipMemsetAsync(ws + OFF_CNT, 0, 2048 + 128, stream);
  hipMemsetAsync(d_out, 0, (size_t)T_TOK * H_DIM * sizeof(float), stream);

  k_pre<<<7168, 256, 0, stream>>>(x, rw, gw, uw, dw, xbf, tope, topw, gws, uws, dws);
  k_hist<<<T_TOK * 2 / 256, 256, 0, stream>>>(tope, counts);
  k_offsets<<<1, 64, 0, stream>>>(counts, offs);
  k_scatter<<<T_TOK / 256, 256, 0, stream>>>(tope, topw, offs, cursors, stok, swt);
  k_gateup<<<dim3(8, T_TOK * 2 / 128, E_NUM), 256, 0, stream>>>(
      xbf, gws, uws, stok, counts, offs, hid);
  k_down<<<dim3(2, T_TOK * 2 / 64, E_NUM), 256, 0, stream>>>(
      hid, dws, stok, swt, counts, offs, out);
}

// Round 5
// 158.145 us; speedup vs baseline: 1.0935x; 1.0935x over previous
//
#include <hip/hip_runtime.h>
#include <cstdint>
#include <cstddef>

#define T_TOK 8192
#define H_DIM 512
#define E_NUM 16
#define F_DIM 1024

typedef __bf16 bf16x8 __attribute__((ext_vector_type(8)));
typedef float f32x4 __attribute__((ext_vector_type(4)));

// ws layout (bytes) — total ~92.6 MB
#define OFF_XBF  0UL          // 8192*512*2            = 8,388,608
#define OFF_HID  8388608UL    // 16384*1024*2          = 33,554,432
#define OFF_GW   41943040UL   // 16 MB bf16 tiled gate; REUSED as ybuf (16 MiB) by k_down/k_gather
#define OFF_UW   58720256UL   // 16 MB bf16 tiled up
#define OFF_DW   75497472UL   // 16 MB bf16 tiled down
#define OFF_STOK 92274688UL
#define OFF_SW   92340224UL
#define OFF_TOPE 92405760UL
#define OFF_TOPW 92471296UL
#define OFF_CNT  92536832UL
#define OFF_CUR  92537856UL
#define OFF_OFFS 92538880UL
#define OFF_SIDX 92539904UL   // 16384 ints: token -> slot
#define OFF_YB   OFF_GW

__device__ __forceinline__ unsigned short f2bf(float f) {
  union { float f; uint32_t u; } v; v.f = f;
  uint32_t r = v.u + 0x7fffu + ((v.u >> 16) & 1u);
  return (unsigned short)(r >> 16);
}

__device__ __forceinline__ float bf2f(unsigned short u) {
  union { uint32_t u; float f; } v; v.u = (uint32_t)u << 16;
  return v.f;
}

__device__ __forceinline__ void gld16(const void* g, void* l) {
  __builtin_amdgcn_global_load_lds(
      (const __attribute__((address_space(1))) unsigned int*)g,
      (__attribute__((address_space(3))) unsigned int*)l, 16, 0, 0);
}

// ---------------- fused pre-pass: weight prep (gu, dw) + router ----------------
__global__ __launch_bounds__(256) void k_pre(
    const float* __restrict__ x, const float* __restrict__ rw,
    const float* __restrict__ gw, const float* __restrict__ uw,
    const float* __restrict__ dw,
    unsigned short* __restrict__ xbf, int* __restrict__ tope,
    float* __restrict__ topw,
    unsigned short* __restrict__ gws, unsigned short* __restrict__ uws,
    unsigned short* __restrict__ dws) {
  const int bid = blockIdx.x;
  const int tid = threadIdx.x;
  __shared__ float ls[32 * 260];

  if (bid < 4096) {
    // ---- gate/up prep: tiles [e][ftile=8][kchunk=16] of [128 f][4 slots of 16B]
    const int fx = bid & 7, kc = (bid >> 3) & 15, ez = bid >> 7;
    const int e = ez >> 1;
    const float* src = ((ez & 1) ? uw : gw) + (size_t)e * H_DIM * F_DIM;
    unsigned short* dst = ((ez & 1) ? uws : gws);
    #pragma unroll
    for (int j = 0; j < 4; ++j) {
      int vi = tid + j * 256;
      int row = vi >> 5, c4 = (vi & 31) * 4;
      float4 v = *(const float4*)&src[(size_t)(kc*32 + row) * F_DIM + fx*128 + c4];
      ls[row*132 + c4+0]=v.x; ls[row*132 + c4+1]=v.y;
      ls[row*132 + c4+2]=v.z; ls[row*132 + c4+3]=v.w;
    }
    __syncthreads();
    size_t obase = (((size_t)e * 8 + fx) * 16 + kc) * 4096;  // ushorts
    #pragma unroll
    for (int j = 0; j < 2; ++j) {
      int oi = tid + j * 256;
      int f = oi >> 2, slot = oi & 3;
      int ks = ((slot ^ f) & 3) * 8;
      uint4 o;
      o.x = (uint32_t)f2bf(ls[(ks+0)*132 + f]) | ((uint32_t)f2bf(ls[(ks+1)*132 + f]) << 16);
      o.y = (uint32_t)f2bf(ls[(ks+2)*132 + f]) | ((uint32_t)f2bf(ls[(ks+3)*132 + f]) << 16);
      o.z = (uint32_t)f2bf(ls[(ks+4)*132 + f]) | ((uint32_t)f2bf(ls[(ks+5)*132 + f]) << 16);
      o.w = (uint32_t)f2bf(ls[(ks+6)*132 + f]) | ((uint32_t)f2bf(ls[(ks+7)*132 + f]) << 16);
      *(uint4*)&dst[obase + (size_t)oi * 8] = o;
    }
  } else if (bid < 5120) {
    // ---- down prep: tiles [e][htile=2][kchunk=32] of [256 h][4 slots]
    const int i = bid - 4096;
    const int ht = i & 1, kc = (i >> 1) & 31, e = i >> 6;
    const float* src = dw + (size_t)e * F_DIM * H_DIM;
    #pragma unroll
    for (int j = 0; j < 8; ++j) {
      int vi = tid + j * 256;
      int row = vi >> 6, c4 = (vi & 63) * 4;
      float4 v = *(const float4*)&src[(size_t)(kc*32 + row) * H_DIM + ht*256 + c4];
      ls[row*260 + c4+0]=v.x; ls[row*260 + c4+1]=v.y;
      ls[row*260 + c4+2]=v.z; ls[row*260 + c4+3]=v.w;
    }
    __syncthreads();
    size_t obase = (((size_t)e * 2 + ht) * 32 + kc) * 8192;  // ushorts
    #pragma unroll
    for (int j = 0; j < 4; ++j) {
      int oi = tid + j * 256;
      int h = oi >> 2, slot = oi & 3;
      int ks = ((slot ^ h) & 3) * 8;
      uint4 o;
      o.x = (uint32_t)f2bf(ls[(ks+0)*260 + h]) | ((uint32_t)f2bf(ls[(ks+1)*260 + h]) << 16);
      o.y = (uint32_t)f2bf(ls[(ks+2)*260 + h]) | ((uint32_t)f2bf(ls[(ks+3)*260 + h]) << 16);
      o.z = (uint32_t)f2bf(ls[(ks+4)*260 + h]) | ((uint32_t)f2bf(ls[(ks+5)*260 + h]) << 16);
      o.w = (uint32_t)f2bf(ls[(ks+6)*260 + h]) | ((uint32_t)f2bf(ls[(ks+7)*260 + h]) << 16);
      *(uint4*)&dws[obase + (size_t)oi * 8] = o;
    }
  } else {
    // ---- router: wave per token
    const int rb = bid - 5120;
    const int wave = tid >> 6, lane = tid & 63;
    const int t = rb * 4 + wave;
    const float4* xr = (const float4*)(x + (size_t)t * H_DIM + lane * 8);
    float4 a = xr[0], b = xr[1];
    float xi[8] = {a.x, a.y, a.z, a.w, b.x, b.y, b.z, b.w};
    uint4 o;
    o.x = (uint32_t)f2bf(xi[0]) | ((uint32_t)f2bf(xi[1]) << 16);
    o.y = (uint32_t)f2bf(xi[2]) | ((uint32_t)f2bf(xi[3]) << 16);
    o.z = (uint32_t)f2bf(xi[4]) | ((uint32_t)f2bf(xi[5]) << 16);
    o.w = (uint32_t)f2bf(xi[6]) | ((uint32_t)f2bf(xi[7]) << 16);
    *(uint4*)(xbf + (size_t)t * H_DIM + lane * 8) = o;
    float acc[E_NUM];
    #pragma unroll
    for (int e = 0; e < E_NUM; ++e) {
      const float4* wr = (const float4*)(rw + e * H_DIM + lane * 8);
      float4 wa = wr[0], wb = wr[1];
      acc[e] = xi[0]*wa.x + xi[1]*wa.y + xi[2]*wa.z + xi[3]*wa.w
             + xi[4]*wb.x + xi[5]*wb.y + xi[6]*wb.z + xi[7]*wb.w;
    }
    #pragma unroll
    for (int off = 1; off < 64; off <<= 1) {
      #pragma unroll
      for (int e = 0; e < E_NUM; ++e) acc[e] += __shfl_xor(acc[e], off);
    }
    if (lane == 0) {
      int e0 = 0; float v0 = acc[0];
      #pragma unroll
      for (int e = 1; e < E_NUM; ++e) if (acc[e] > v0) { v0 = acc[e]; e0 = e; }
      int e1 = -1; float v1 = -3.4e38f;
      #pragma unroll
      for (int e = 0; e < E_NUM; ++e) if (e != e0 && acc[e] > v1) { v1 = acc[e]; e1 = e; }
      float ee = __expf(v1 - v0);
      float inv = 1.0f / (1.0f + ee);
      tope[t*2]   = e0; tope[t*2+1] = e1;
      topw[t*2]   = inv; topw[t*2+1] = ee * inv;
    }
  }
}

__global__ __launch_bounds__(256) void k_hist(
    const int* __restrict__ tope, int* __restrict__ counts) {
  __shared__ int lh[E_NUM];
  const int tid = threadIdx.x;
  if (tid < E_NUM) lh[tid] = 0;
  __syncthreads();
  atomicAdd(&lh[tope[blockIdx.x * 256 + tid]], 1);
  __syncthreads();
  if (tid < E_NUM) atomicAdd(&counts[tid * 16], lh[tid]);
}

__global__ void k_offsets(const int* __restrict__ counts, int* __restrict__ offs) {
  if (threadIdx.x == 0 && blockIdx.x == 0) {
    int s = 0;
    for (int e = 0; e < E_NUM; ++e) { offs[e] = s; s += counts[e * 16]; }
    offs[E_NUM] = s;
  }
}

__global__ __launch_bounds__(256) void k_scatter(
    const int* __restrict__ tope, const float* __restrict__ topw,
    const int* __restrict__ offs, int* __restrict__ cursors,
    int* __restrict__ stok, float* __restrict__ sw, int* __restrict__ sidx) {
  __shared__ int lh[E_NUM];
  __shared__ int lbase[E_NUM];
  const int tid = threadIdx.x;
  const int t = blockIdx.x * 256 + tid;
  if (tid < E_NUM) lh[tid] = 0;
  __syncthreads();
  int e0 = tope[t*2], e1 = tope[t*2+1];
  int r0 = atomicAdd(&lh[e0], 1);
  int r1 = atomicAdd(&lh[e1], 1);
  __syncthreads();
  if (tid < E_NUM) lbase[tid] = atomicAdd(&cursors[tid * 16], lh[tid]);
  __syncthreads();
  int s0 = offs[e0] + lbase[e0] + r0;
  int s1 = offs[e1] + lbase[e1] + r1;
  stok[s0] = t; sw[s0] = topw[t*2];
  stok[s1] = t; sw[s1] = topw[t*2+1];
  sidx[t*2] = s0; sidx[t*2+1] = s1;
}

// ---------------- gate/up GEMM + SiLU ----------------
// block: 128 tokens x 128 f, 4 waves (2x2), BK=32, 16 chunks, global_load_lds + swizzle
__global__ __launch_bounds__(256, 2) void k_gateup(
    const unsigned short* __restrict__ xbf,
    const unsigned short* __restrict__ gws, const unsigned short* __restrict__ uws,
    const int* __restrict__ stok, const int* __restrict__ counts,
    const int* __restrict__ offs, unsigned short* __restrict__ hid) {
  const int e = blockIdx.z;
  const int cnt = counts[e * 16];
  const int t0 = blockIdx.y * 128;
  if (t0 >= cnt) return;
  const int base = offs[e];
  const int fx = blockIdx.x;

  __shared__ __align__(16) unsigned short sb[2][3][4096];  // A,G,U  48 KB

  const int tid = threadIdx.x;
  const int wave = tid >> 6, lane = tid & 63;
  const int l15 = lane & 15, hi = lane >> 4;
  const int wm = wave >> 1, wn = wave & 1;

  const int r0 = tid >> 2, slot = tid & 3;
  const int rr0 = min(t0 + r0, cnt - 1), rr1 = min(t0 + r0 + 64, cnt - 1);
  const char* sA0 = (const char*)xbf + (size_t)stok[base + rr0] * 1024 + ((slot ^ (r0 & 3)) * 16);
  const char* sA1 = (const char*)xbf + (size_t)stok[base + rr1] * 1024 + ((slot ^ (r0 & 3)) * 16);
  const char* sG = (const char*)gws + (((size_t)e * 8 + fx) * 16) * 8192 + tid * 16;
  const char* sU = (const char*)uws + (((size_t)e * 8 + fx) * 16) * 8192 + tid * 16;
  unsigned short* const dA = &sb[0][0][wave * 512];
  unsigned short* const dG = &sb[0][1][wave * 512];
  unsigned short* const dU = &sb[0][2][wave * 512];
  const int bufo = 3 * 4096;  // ushort stride between buffers

  f32x4 accg[4][4] = {}; f32x4 accu[4][4] = {};

  #define STAGE_GU(b, kk) { \
    gld16(sA0 + (kk)*64, dA + (b)*bufo); \
    gld16(sA1 + (kk)*64, dA + (b)*bufo + 2048); \
    gld16(sG + (size_t)(kk)*8192, dG + (b)*bufo); \
    gld16(sG + (size_t)(kk)*8192 + 4096, dG + (b)*bufo + 2048); \
    gld16(sU + (size_t)(kk)*8192, dU + (b)*bufo); \
    gld16(sU + (size_t)(kk)*8192 + 4096, dU + (b)*bufo + 2048); }

  STAGE_GU(0, 0);
  __syncthreads();
  #pragma unroll 1
  for (int kk = 0; kk < 16; ++kk) {
    const int cur = kk & 1;
    if (kk < 15) STAGE_GU(cur ^ 1, kk + 1);
    const unsigned short* lA = &sb[cur][0][0];
    const unsigned short* lG = &sb[cur][1][0];
    const unsigned short* lU = &sb[cur][2][0];
    bf16x8 a[4], bg[4], bu[4];
    #pragma unroll
    for (int m = 0; m < 4; ++m) {
      int row = wm*64 + m*16 + l15;
      a[m] = *(const bf16x8*)((const char*)lA + row*64 + (((hi ^ row) & 3) << 4));
    }
    #pragma unroll
    for (int s = 0; s < 4; ++s) {
      int row = wn*64 + s*16 + l15;
      int o = row*64 + (((hi ^ row) & 3) << 4);
      bg[s] = *(const bf16x8*)((const char*)lG + o);
      bu[s] = *(const bf16x8*)((const char*)lU + o);
    }
    #pragma unroll
    for (int m = 0; m < 4; ++m)
      #pragma unroll
      for (int s = 0; s < 4; ++s) {
        accg[m][s] = __builtin_amdgcn_mfma_f32_16x16x32_bf16(a[m], bg[s], accg[m][s], 0, 0, 0);
        accu[m][s] = __builtin_amdgcn_mfma_f32_16x16x32_bf16(a[m], bu[s], accu[m][s], 0, 0, 0);
      }
    __syncthreads();
  }
  #undef STAGE_GU

  #pragma unroll
  for (int m = 0; m < 4; ++m)
    #pragma unroll
    for (int r = 0; r < 4; ++r) {
      int row = t0 + wm*64 + m*16 + hi*4 + r;
      if (row < cnt) {
        #pragma unroll
        for (int s = 0; s < 4; ++s) {
          float g = accg[m][s][r], u = accu[m][s][r];
          float h = g / (1.0f + __expf(-g)) * u;
          hid[(size_t)(base + row) * 1024 + fx*128 + wn*64 + s*16 + l15] = f2bf(h);
        }
      }
    }
}

// ---------------- down GEMM -> per-slot ybuf (NO atomics) ----------------
// block: 64 tokens x 256 h, 4 waves (1m x 4n, wave = 64t x 64h), BK=32, 32 chunks
__global__ __launch_bounds__(256, 3) void k_down(
    const unsigned short* __restrict__ hid, const unsigned short* __restrict__ dws,
    const int* __restrict__ counts, const int* __restrict__ offs,
    unsigned short* __restrict__ ybuf) {
  const int e = blockIdx.z;
  const int cnt = counts[e * 16];
  const int t0 = blockIdx.y * 64;
  if (t0 >= cnt) return;
  const int base = offs[e];
  const int ht = blockIdx.x;

  __shared__ __align__(16) unsigned short sbA[2][2048];   // 8 KB
  __shared__ __align__(16) unsigned short sbW[2][8192];   // 32 KB

  const int tid = threadIdx.x;
  const int wave = tid >> 6, lane = tid & 63;
  const int l15 = lane & 15, hi = lane >> 4;

  const int r0 = tid >> 2, slot = tid & 3;
  const int rr = min(t0 + r0, cnt - 1);
  const char* sA = (const char*)hid + (size_t)(base + rr) * 2048 + ((slot ^ (r0 & 3)) * 16);
  const char* sW = (const char*)dws + (((size_t)e * 2 + ht) * 32) * 16384 + tid * 16;
  unsigned short* const dA = &sbA[0][wave * 512];
  unsigned short* const dW = &sbW[0][wave * 512];

  f32x4 acc[4][4] = {};

  #define STAGE_DN(b, kk) { \
    gld16(sA + (kk)*64, dA + (b)*2048); \
    const char* w = sW + (size_t)(kk)*16384; \
    gld16(w,         dW + (b)*8192); \
    gld16(w + 4096,  dW + (b)*8192 + 2048); \
    gld16(w + 8192,  dW + (b)*8192 + 4096); \
    gld16(w + 12288, dW + (b)*8192 + 6144); }

  STAGE_DN(0, 0);
  __syncthreads();
  #pragma unroll 1
  for (int kk = 0; kk < 32; ++kk) {
    const int cur = kk & 1;
    if (kk < 31) STAGE_DN(cur ^ 1, kk + 1);
    const unsigned short* lA = &sbA[cur][0];
    const unsigned short* lW = &sbW[cur][0];
    bf16x8 a[4], b[4];
    #pragma unroll
    for (int m = 0; m < 4; ++m) {
      int row = m*16 + l15;
      a[m] = *(const bf16x8*)((const char*)lA + row*64 + (((hi ^ row) & 3) << 4));
    }
    #pragma unroll
    for (int s = 0; s < 4; ++s) {
      int row = wave*64 + s*16 + l15;
      b[s] = *(const bf16x8*)((const char*)lW + row*64 + (((hi ^ row) & 3) << 4));
    }
    #pragma unroll
    for (int m = 0; m < 4; ++m)
      #pragma unroll
      for (int s = 0; s < 4; ++s)
        acc[m][s] = __builtin_amdgcn_mfma_f32_16x16x32_bf16(a[m], b[s], acc[m][s], 0, 0, 0);
    __syncthreads();
  }
  #undef STAGE_DN

  #pragma unroll
  for (int m = 0; m < 4; ++m)
    #pragma unroll
    for (int r = 0; r < 4; ++r) {
      int row = t0 + m*16 + hi*4 + r;
      if (row < cnt) {
        unsigned short* y = ybuf + (size_t)(base + row) * 512 + ht*256 + wave*64;
        #pragma unroll
        for (int s = 0; s < 4; ++s)
          y[s*16 + l15] = f2bf(acc[m][s][r]);
      }
    }
}

// ---------------- gather: out[t] = w0*y[s0] + w1*y[s1] (plain stores) ----------------
__global__ __launch_bounds__(256) void k_gather(
    const unsigned short* __restrict__ ybuf, const int* __restrict__ sidx,
    const float* __restrict__ topw, float* __restrict__ out) {
  const int wave = threadIdx.x >> 6, lane = threadIdx.x & 63;
  const int t = blockIdx.x * 4 + wave;
  const int s0 = sidx[t*2], s1 = sidx[t*2+1];
  const float w0 = topw[t*2], w1 = topw[t*2+1];
  uint4 a = *(const uint4*)(ybuf + (size_t)s0 * 512 + lane * 8);
  uint4 b = *(const uint4*)(ybuf + (size_t)s1 * 512 + lane * 8);
  float4 o0, o1;
  o0.x = w0*bf2f((unsigned short)(a.x)) + w1*bf2f((unsigned short)(b.x));
  o0.y = w0*bf2f((unsigned short)(a.x>>16)) + w1*bf2f((unsigned short)(b.x>>16));
  o0.z = w0*bf2f((unsigned short)(a.y)) + w1*bf2f((unsigned short)(b.y));
  o0.w = w0*bf2f((unsigned short)(a.y>>16)) + w1*bf2f((unsigned short)(b.y>>16));
  o1.x = w0*bf2f((unsigned short)(a.z)) + w1*bf2f((unsigned short)(b.z));
  o1.y = w0*bf2f((unsigned short)(a.z>>16)) + w1*bf2f((unsigned short)(b.z>>16));
  o1.z = w0*bf2f((unsigned short)(a.w)) + w1*bf2f((unsigned short)(b.w));
  o1.w = w0*bf2f((unsigned short)(a.w>>16)) + w1*bf2f((unsigned short)(b.w>>16));
  float* orow = out + (size_t)t * H_DIM + lane * 8;
  *(float4*)orow = o0;
  *(float4*)(orow + 4) = o1;
}

extern "C" void kernel_launch(void* const* d_in, const int* in_sizes, int n_in,
                              void* d_out, int out_size, void* d_ws, size_t ws_size,
                              hipStream_t stream) {
  const float* x  = (const float*)d_in[0];
  const float* rw = (const float*)d_in[1];
  const float* gw = (const float*)d_in[2];
  const float* uw = (const float*)d_in[3];
  const float* dw = (const float*)d_in[4];
  float* out = (float*)d_out;
  char* ws = (char*)d_ws;

  unsigned short* xbf = (unsigned short*)(ws + OFF_XBF);
  unsigned short* hid = (unsigned short*)(ws + OFF_HID);
  unsigned short* gws = (unsigned short*)(ws + OFF_GW);
  unsigned short* uws = (unsigned short*)(ws + OFF_UW);
  unsigned short* dws = (unsigned short*)(ws + OFF_DW);
  unsigned short* ybuf = (unsigned short*)(ws + OFF_YB);  // aliases gws (dead after gateup)
  int*   stok    = (int*)(ws + OFF_STOK);
  float* swt     = (float*)(ws + OFF_SW);
  int*   tope    = (int*)(ws + OFF_TOPE);
  float* topw    = (float*)(ws + OFF_TOPW);
  int*   counts  = (int*)(ws + OFF_CNT);
  int*   cursors = (int*)(ws + OFF_CUR);
  int*   offs    = (int*)(ws + OFF_OFFS);
  int*   sidx    = (int*)(ws + OFF_SIDX);

  hipMemsetAsync(ws + OFF_CNT, 0, 2048 + 128, stream);

  k_pre<<<7168, 256, 0, stream>>>(x, rw, gw, uw, dw, xbf, tope, topw, gws, uws, dws);
  k_hist<<<T_TOK * 2 / 256, 256, 0, stream>>>(tope, counts);
  k_offsets<<<1, 64, 0, stream>>>(counts, offs);
  k_scatter<<<T_TOK / 256, 256, 0, stream>>>(tope, topw, offs, cursors, stok, swt, sidx);
  k_gateup<<<dim3(8, T_TOK * 2 / 128, E_NUM), 256, 0, stream>>>(
      xbf, gws, uws, stok, counts, offs, hid);
  k_down<<<dim3(2, T_TOK * 2 / 64, E_NUM), 256, 0, stream>>>(
      hid, dws, counts, offs, ybuf);
  k_gather<<<T_TOK / 4, 256, 0, stream>>>(ybuf, sidx, topw, out);
}

// Round 6
// 153.937 us; speedup vs baseline: 1.1234x; 1.0273x over previous
//
#include <hip/hip_runtime.h>
#include <cstdint>
#include <cstddef>

#define T_TOK 8192
#define H_DIM 512
#define E_NUM 16
#define F_DIM 1024

typedef __bf16 bf16x8 __attribute__((ext_vector_type(8)));
typedef float f32x4 __attribute__((ext_vector_type(4)));

// ws layout (bytes)
#define OFF_XBF  0UL          // 8192*512*2
#define OFF_HID  8388608UL    // 16640*1024*2 (rounded region)
#define OFF_GW   41943040UL   // 16 MB bf16 tiled gate; REUSED as ybuf after gateup
#define OFF_UW   58720256UL   // 16 MB bf16 tiled up
#define OFF_DW   75497472UL   // 16 MB bf16 tiled down
#define OFF_STOK 92274688UL
#define OFF_SW   92340224UL
#define OFF_TOPE 92405760UL
#define OFF_TOPW 92471296UL
#define OFF_CNT  92536832UL   // 16 experts * 16 ints (padded)
#define OFF_CUR  92537856UL
#define OFF_OFFS 92538880UL   // offs[0..16], [18]=nt128, [19]=nt64
#define OFF_SIDX 92539904UL   // 16384 ints
#define OFF_L128 92605440UL   // 256 ints
#define OFF_L64  92606464UL   // 512 ints
#define OFF_YB   OFF_GW

__device__ __forceinline__ unsigned short f2bf(float f) {
  union { float f; uint32_t u; } v; v.f = f;
  uint32_t r = v.u + 0x7fffu + ((v.u >> 16) & 1u);
  return (unsigned short)(r >> 16);
}

__device__ __forceinline__ float bf2f(unsigned short u) {
  union { uint32_t u; float f; } v; v.u = (uint32_t)u << 16;
  return v.f;
}

__device__ __forceinline__ void gld16(const void* g, void* l) {
  __builtin_amdgcn_global_load_lds(
      (const __attribute__((address_space(1))) unsigned int*)g,
      (__attribute__((address_space(3))) unsigned int*)l, 16, 0, 0);
}

// ---------------- fused pre-pass ----------------
// bid [0,2048):    gate/up convert+transpose, tile [32 k][256 f]
// bid [2048,3072): down    convert+transpose, tile [32 k][256 h]
// bid [3072,5120): router (wave per token) + x->bf16
// Transpose tile: reg-patch [8k x 4n] per thread -> 4x ds_write_b128 chunks
// (bank-swizzled) -> 4x ds_read_b128 -> global in GEMM slot format.
__global__ __launch_bounds__(256) void k_pre(
    const float* __restrict__ x, const float* __restrict__ rw,
    const float* __restrict__ gw, const float* __restrict__ uw,
    const float* __restrict__ dw,
    unsigned short* __restrict__ xbf, int* __restrict__ tope,
    float* __restrict__ topw,
    unsigned short* __restrict__ gws, unsigned short* __restrict__ uws,
    unsigned short* __restrict__ dws) {
  const int bid = blockIdx.x;
  const int tid = threadIdx.x;
  __shared__ __align__(16) uint32_t lsu[4096];  // 16 KB chunk image

  if (bid < 3072) {
    const int isgu = (bid < 2048);
    const float* src;
    unsigned short* dst;
    size_t obase0;   // u16 offset of this tile's (fx=0) output chunk
    int ldn;
    int e, kc;
    if (isgu) {
      e = bid >> 7;
      const int mat = (bid >> 6) & 1;
      kc = (bid >> 2) & 15;
      const int f2 = bid & 3;
      src = (mat ? uw : gw) + (size_t)e * H_DIM * F_DIM + (size_t)kc * 32 * F_DIM + f2 * 256;
      dst = mat ? uws : gws;
      obase0 = (((size_t)e * 8 + f2 * 2) * 16 + kc) * 4096;
      ldn = F_DIM;
    } else {
      const int r = bid - 2048;
      e = r >> 6;
      kc = (r >> 1) & 31;
      const int ht = r & 1;
      src = dw + (size_t)e * F_DIM * H_DIM + (size_t)kc * 32 * H_DIM + ht * 256;
      dst = dws;
      obase0 = (((size_t)e * 2 + ht) * 32 + kc) * 8192;
      ldn = H_DIM;
    }
    // phase 1: [8k x 4n] reg patch -> 4 swizzled b128 chunks
    const int nb = tid & 63, kb = tid >> 6;
    const float* s0 = src + (size_t)kb * 8 * ldn + nb * 4;
    float4 v[8];
    #pragma unroll
    for (int j = 0; j < 8; ++j) v[j] = *(const float4*)(s0 + (size_t)j * ldn);
    #pragma unroll
    for (int i = 0; i < 4; ++i) {
      const int n = nb * 4 + i;
      uint4 q;
      q.x = (uint32_t)f2bf(((const float*)&v[0])[i]) | ((uint32_t)f2bf(((const float*)&v[1])[i]) << 16);
      q.y = (uint32_t)f2bf(((const float*)&v[2])[i]) | ((uint32_t)f2bf(((const float*)&v[3])[i]) << 16);
      q.z = (uint32_t)f2bf(((const float*)&v[4])[i]) | ((uint32_t)f2bf(((const float*)&v[5])[i]) << 16);
      q.w = (uint32_t)f2bf(((const float*)&v[6])[i]) | ((uint32_t)f2bf(((const float*)&v[7])[i]) << 16);
      const int jr = n >> 1, sw = (jr ^ (jr >> 3)) & 7;
      const int ccs = (((n & 1) << 2) + kb) ^ sw;
      *(uint4*)&lsu[jr * 32 + ccs * 4] = q;
    }
    __syncthreads();
    // phase 2: read chunks (n=tid, c=0..3), store in GEMM slot format
    const int n = tid;
    const int jr = n >> 1, sw = (jr ^ (jr >> 3)) & 7;
    #pragma unroll
    for (int c = 0; c < 4; ++c) {
      const int ccs = (((n & 1) << 2) + c) ^ sw;
      uint4 q = *(const uint4*)&lsu[jr * 32 + ccs * 4];
      if (isgu) {
        const int fi = n & 127, s = (c ^ fi) & 3;
        const size_t ob = obase0 + (size_t)(n >> 7) * 16 * 4096;  // fx advance
        *(uint4*)&dst[ob + fi * 32 + s * 8] = q;
      } else {
        const int s = (c ^ n) & 3;
        *(uint4*)&dst[obase0 + n * 32 + s * 8] = q;
      }
    }
  } else {
    // ---- router: wave per token
    const int rb = bid - 3072;
    const int wave = tid >> 6, lane = tid & 63;
    const int t = rb * 4 + wave;
    const float4* xr = (const float4*)(x + (size_t)t * H_DIM + lane * 8);
    float4 a = xr[0], b = xr[1];
    float xi[8] = {a.x, a.y, a.z, a.w, b.x, b.y, b.z, b.w};
    uint4 o;
    o.x = (uint32_t)f2bf(xi[0]) | ((uint32_t)f2bf(xi[1]) << 16);
    o.y = (uint32_t)f2bf(xi[2]) | ((uint32_t)f2bf(xi[3]) << 16);
    o.z = (uint32_t)f2bf(xi[4]) | ((uint32_t)f2bf(xi[5]) << 16);
    o.w = (uint32_t)f2bf(xi[6]) | ((uint32_t)f2bf(xi[7]) << 16);
    *(uint4*)(xbf + (size_t)t * H_DIM + lane * 8) = o;
    float acc[E_NUM];
    #pragma unroll
    for (int e = 0; e < E_NUM; ++e) {
      const float4* wr = (const float4*)(rw + e * H_DIM + lane * 8);
      float4 wa = wr[0], wb = wr[1];
      acc[e] = xi[0]*wa.x + xi[1]*wa.y + xi[2]*wa.z + xi[3]*wa.w
             + xi[4]*wb.x + xi[5]*wb.y + xi[6]*wb.z + xi[7]*wb.w;
    }
    #pragma unroll
    for (int off = 1; off < 64; off <<= 1) {
      #pragma unroll
      for (int e = 0; e < E_NUM; ++e) acc[e] += __shfl_xor(acc[e], off);
    }
    if (lane == 0) {
      int e0 = 0; float v0 = acc[0];
      #pragma unroll
      for (int e = 1; e < E_NUM; ++e) if (acc[e] > v0) { v0 = acc[e]; e0 = e; }
      int e1 = -1; float v1 = -3.4e38f;
      #pragma unroll
      for (int e = 0; e < E_NUM; ++e) if (e != e0 && acc[e] > v1) { v1 = acc[e]; e1 = e; }
      float ee = __expf(v1 - v0);
      float inv = 1.0f / (1.0f + ee);
      tope[t*2]   = e0; tope[t*2+1] = e1;
      topw[t*2]   = inv; topw[t*2+1] = ee * inv;
    }
  }
}

__global__ __launch_bounds__(256) void k_hist(
    const int* __restrict__ tope, int* __restrict__ counts) {
  __shared__ int lh[E_NUM];
  const int tid = threadIdx.x;
  if (tid < E_NUM) lh[tid] = 0;
  __syncthreads();
  atomicAdd(&lh[tope[blockIdx.x * 256 + tid]], 1);
  __syncthreads();
  if (tid < E_NUM) atomicAdd(&counts[tid * 16], lh[tid]);
}

// offsets + compact tile work-lists (128- and 64-token grains)
__global__ void k_offsets(const int* __restrict__ counts, int* __restrict__ offs,
                          int* __restrict__ list128, int* __restrict__ list64) {
  __shared__ int sc[16], b128[16], b64[16];
  if (threadIdx.x == 0) {
    int s = 0, a = 0, b = 0;
    for (int e = 0; e < E_NUM; ++e) {
      int c = counts[e * 16];
      sc[e] = c; b128[e] = a; b64[e] = b;
      offs[e] = s;
      s += c; a += (c + 127) >> 7; b += (c + 63) >> 6;
    }
    offs[16] = s; offs[18] = a; offs[19] = b;
  }
  __syncthreads();
  for (int e = 0; e < E_NUM; ++e) {
    const int n1 = (sc[e] + 127) >> 7;
    for (int ti = threadIdx.x; ti < n1; ti += 64) list128[b128[e] + ti] = (e << 24) | (ti << 7);
    const int n2 = (sc[e] + 63) >> 6;
    for (int ti = threadIdx.x; ti < n2; ti += 64) list64[b64[e] + ti] = (e << 24) | (ti << 6);
  }
}

__global__ __launch_bounds__(256) void k_scatter(
    const int* __restrict__ tope, const float* __restrict__ topw,
    const int* __restrict__ offs, int* __restrict__ cursors,
    int* __restrict__ stok, float* __restrict__ sw, int* __restrict__ sidx) {
  __shared__ int lh[E_NUM];
  __shared__ int lbase[E_NUM];
  const int tid = threadIdx.x;
  const int t = blockIdx.x * 256 + tid;
  if (tid < E_NUM) lh[tid] = 0;
  __syncthreads();
  int e0 = tope[t*2], e1 = tope[t*2+1];
  int r0 = atomicAdd(&lh[e0], 1);
  int r1 = atomicAdd(&lh[e1], 1);
  __syncthreads();
  if (tid < E_NUM) lbase[tid] = atomicAdd(&cursors[tid * 16], lh[tid]);
  __syncthreads();
  int s0 = offs[e0] + lbase[e0] + r0;
  int s1 = offs[e1] + lbase[e1] + r1;
  stok[s0] = t; sw[s0] = topw[t*2];
  stok[s1] = t; sw[s1] = topw[t*2+1];
  sidx[t*2] = s0; sidx[t*2+1] = s1;
}

// ---------------- gate/up GEMM + SiLU ----------------
// compact work-list; block: 128 tok x 128 f, 4 waves (2x2), BK=32
__global__ __launch_bounds__(256, 2) void k_gateup(
    const unsigned short* __restrict__ xbf,
    const unsigned short* __restrict__ gws, const unsigned short* __restrict__ uws,
    const int* __restrict__ stok, const int* __restrict__ counts,
    const int* __restrict__ offs, const int* __restrict__ list128,
    unsigned short* __restrict__ hid) {
  const int y = blockIdx.y;
  if (y >= offs[18]) return;
  const int v = list128[y];
  const int e = v >> 24, t0 = v & 0xffffff;
  const int cnt = counts[e * 16];
  const int base = offs[e];
  const int fx = blockIdx.x;

  __shared__ __align__(16) unsigned short sb[2][3][4096];  // A,G,U  48 KB

  const int tid = threadIdx.x;
  const int wave = tid >> 6, lane = tid & 63;
  const int l15 = lane & 15, hi = lane >> 4;
  const int wm = wave >> 1, wn = wave & 1;

  const int r0 = tid >> 2, slot = tid & 3;
  const int rr0 = min(t0 + r0, cnt - 1), rr1 = min(t0 + r0 + 64, cnt - 1);
  const char* sA0 = (const char*)xbf + (size_t)stok[base + rr0] * 1024 + ((slot ^ (r0 & 3)) * 16);
  const char* sA1 = (const char*)xbf + (size_t)stok[base + rr1] * 1024 + ((slot ^ (r0 & 3)) * 16);
  const char* sG = (const char*)gws + (((size_t)e * 8 + fx) * 16) * 8192 + tid * 16;
  const char* sU = (const char*)uws + (((size_t)e * 8 + fx) * 16) * 8192 + tid * 16;
  unsigned short* const dA = &sb[0][0][wave * 512];
  unsigned short* const dG = &sb[0][1][wave * 512];
  unsigned short* const dU = &sb[0][2][wave * 512];
  const int bufo = 3 * 4096;

  f32x4 accg[4][4] = {}; f32x4 accu[4][4] = {};

  #define STAGE_GU(b, kk) { \
    gld16(sA0 + (kk)*64, dA + (b)*bufo); \
    gld16(sA1 + (kk)*64, dA + (b)*bufo + 2048); \
    gld16(sG + (size_t)(kk)*8192, dG + (b)*bufo); \
    gld16(sG + (size_t)(kk)*8192 + 4096, dG + (b)*bufo + 2048); \
    gld16(sU + (size_t)(kk)*8192, dU + (b)*bufo); \
    gld16(sU + (size_t)(kk)*8192 + 4096, dU + (b)*bufo + 2048); }

  STAGE_GU(0, 0);
  __syncthreads();
  #pragma unroll 1
  for (int kk = 0; kk < 16; ++kk) {
    const int cur = kk & 1;
    if (kk < 15) STAGE_GU(cur ^ 1, kk + 1);
    const unsigned short* lA = &sb[cur][0][0];
    const unsigned short* lG = &sb[cur][1][0];
    const unsigned short* lU = &sb[cur][2][0];
    bf16x8 a[4], bg[4], bu[4];
    #pragma unroll
    for (int m = 0; m < 4; ++m) {
      int row = wm*64 + m*16 + l15;
      a[m] = *(const bf16x8*)((const char*)lA + row*64 + (((hi ^ row) & 3) << 4));
    }
    #pragma unroll
    for (int s = 0; s < 4; ++s) {
      int row = wn*64 + s*16 + l15;
      int o = row*64 + (((hi ^ row) & 3) << 4);
      bg[s] = *(const bf16x8*)((const char*)lG + o);
      bu[s] = *(const bf16x8*)((const char*)lU + o);
    }
    #pragma unroll
    for (int m = 0; m < 4; ++m)
      #pragma unroll
      for (int s = 0; s < 4; ++s) {
        accg[m][s] = __builtin_amdgcn_mfma_f32_16x16x32_bf16(a[m], bg[s], accg[m][s], 0, 0, 0);
        accu[m][s] = __builtin_amdgcn_mfma_f32_16x16x32_bf16(a[m], bu[s], accu[m][s], 0, 0, 0);
      }
    __syncthreads();
  }
  #undef STAGE_GU

  #pragma unroll
  for (int m = 0; m < 4; ++m)
    #pragma unroll
    for (int r = 0; r < 4; ++r) {
      int row = t0 + wm*64 + m*16 + hi*4 + r;
      if (row < cnt) {
        #pragma unroll
        for (int s = 0; s < 4; ++s) {
          float g = accg[m][s][r], u = accu[m][s][r];
          float h = g / (1.0f + __expf(-g)) * u;
          hid[(size_t)(base + row) * 1024 + fx*128 + wn*64 + s*16 + l15] = f2bf(h);
        }
      }
    }
}

// ---------------- down GEMM -> per-slot ybuf (no atomics) ----------------
// compact work-list; block: 64 tok x 256 h, 4 waves (1x4), BK=32
__global__ __launch_bounds__(256, 3) void k_down(
    const unsigned short* __restrict__ hid, const unsigned short* __restrict__ dws,
    const int* __restrict__ counts, const int* __restrict__ offs,
    const int* __restrict__ list64, unsigned short* __restrict__ ybuf) {
  const int y = blockIdx.y;
  if (y >= offs[19]) return;
  const int v = list64[y];
  const int e = v >> 24, t0 = v & 0xffffff;
  const int cnt = counts[e * 16];
  const int base = offs[e];
  const int ht = blockIdx.x;

  __shared__ __align__(16) unsigned short sbA[2][2048];   // 8 KB
  __shared__ __align__(16) unsigned short sbW[2][8192];   // 32 KB

  const int tid = threadIdx.x;
  const int wave = tid >> 6, lane = tid & 63;
  const int l15 = lane & 15, hi = lane >> 4;

  const int r0 = tid >> 2, slot = tid & 3;
  const int rr = min(t0 + r0, cnt - 1);
  const char* sA = (const char*)hid + (size_t)(base + rr) * 2048 + ((slot ^ (r0 & 3)) * 16);
  const char* sW = (const char*)dws + (((size_t)e * 2 + ht) * 32) * 16384 + tid * 16;
  unsigned short* const dA = &sbA[0][wave * 512];
  unsigned short* const dW = &sbW[0][wave * 512];

  f32x4 acc[4][4] = {};

  #define STAGE_DN(b, kk) { \
    gld16(sA + (kk)*64, dA + (b)*2048); \
    const char* w = sW + (size_t)(kk)*16384; \
    gld16(w,         dW + (b)*8192); \
    gld16(w + 4096,  dW + (b)*8192 + 2048); \
    gld16(w + 8192,  dW + (b)*8192 + 4096); \
    gld16(w + 12288, dW + (b)*8192 + 6144); }

  STAGE_DN(0, 0);
  __syncthreads();
  #pragma unroll 1
  for (int kk = 0; kk < 32; ++kk) {
    const int cur = kk & 1;
    if (kk < 31) STAGE_DN(cur ^ 1, kk + 1);
    const unsigned short* lA = &sbA[cur][0];
    const unsigned short* lW = &sbW[cur][0];
    bf16x8 a[4], b[4];
    #pragma unroll
    for (int m = 0; m < 4; ++m) {
      int row = m*16 + l15;
      a[m] = *(const bf16x8*)((const char*)lA + row*64 + (((hi ^ row) & 3) << 4));
    }
    #pragma unroll
    for (int s = 0; s < 4; ++s) {
      int row = wave*64 + s*16 + l15;
      b[s] = *(const bf16x8*)((const char*)lW + row*64 + (((hi ^ row) & 3) << 4));
    }
    #pragma unroll
    for (int m = 0; m < 4; ++m)
      #pragma unroll
      for (int s = 0; s < 4; ++s)
        acc[m][s] = __builtin_amdgcn_mfma_f32_16x16x32_bf16(a[m], b[s], acc[m][s], 0, 0, 0);
    __syncthreads();
  }
  #undef STAGE_DN

  #pragma unroll
  for (int m = 0; m < 4; ++m)
    #pragma unroll
    for (int r = 0; r < 4; ++r) {
      int row = t0 + m*16 + hi*4 + r;
      if (row < cnt) {
        unsigned short* yy = ybuf + (size_t)(base + row) * 512 + ht*256 + wave*64;
        #pragma unroll
        for (int s = 0; s < 4; ++s)
          yy[s*16 + l15] = f2bf(acc[m][s][r]);
      }
    }
}

// ---------------- gather: out[t] = w0*y[s0] + w1*y[s1] ----------------
__global__ __launch_bounds__(256) void k_gather(
    const unsigned short* __restrict__ ybuf, const int* __restrict__ sidx,
    const float* __restrict__ topw, float* __restrict__ out) {
  const int wave = threadIdx.x >> 6, lane = threadIdx.x & 63;
  const int t = blockIdx.x * 4 + wave;
  const int s0 = sidx[t*2], s1 = sidx[t*2+1];
  const float w0 = topw[t*2], w1 = topw[t*2+1];
  uint4 a = *(const uint4*)(ybuf + (size_t)s0 * 512 + lane * 8);
  uint4 b = *(const uint4*)(ybuf + (size_t)s1 * 512 + lane * 8);
  float4 o0, o1;
  o0.x = w0*bf2f((unsigned short)(a.x)) + w1*bf2f((unsigned short)(b.x));
  o0.y = w0*bf2f((unsigned short)(a.x>>16)) + w1*bf2f((unsigned short)(b.x>>16));
  o0.z = w0*bf2f((unsigned short)(a.y)) + w1*bf2f((unsigned short)(b.y));
  o0.w = w0*bf2f((unsigned short)(a.y>>16)) + w1*bf2f((unsigned short)(b.y>>16));
  o1.x = w0*bf2f((unsigned short)(a.z)) + w1*bf2f((unsigned short)(b.z));
  o1.y = w0*bf2f((unsigned short)(a.z>>16)) + w1*bf2f((unsigned short)(b.z>>16));
  o1.z = w0*bf2f((unsigned short)(a.w)) + w1*bf2f((unsigned short)(b.w));
  o1.w = w0*bf2f((unsigned short)(a.w>>16)) + w1*bf2f((unsigned short)(b.w>>16));
  float* orow = out + (size_t)t * H_DIM + lane * 8;
  *(float4*)orow = o0;
  *(float4*)(orow + 4) = o1;
}

extern "C" void kernel_launch(void* const* d_in, const int* in_sizes, int n_in,
                              void* d_out, int out_size, void* d_ws, size_t ws_size,
                              hipStream_t stream) {
  const float* x  = (const float*)d_in[0];
  const float* rw = (const float*)d_in[1];
  const float* gw = (const float*)d_in[2];
  const float* uw = (const float*)d_in[3];
  const float* dw = (const float*)d_in[4];
  float* out = (float*)d_out;
  char* ws = (char*)d_ws;

  unsigned short* xbf = (unsigned short*)(ws + OFF_XBF);
  unsigned short* hid = (unsigned short*)(ws + OFF_HID);
  unsigned short* gws = (unsigned short*)(ws + OFF_GW);
  unsigned short* uws = (unsigned short*)(ws + OFF_UW);
  unsigned short* dws = (unsigned short*)(ws + OFF_DW);
  unsigned short* ybuf = (unsigned short*)(ws + OFF_YB);
  int*   stok    = (int*)(ws + OFF_STOK);
  float* swt     = (float*)(ws + OFF_SW);
  int*   tope    = (int*)(ws + OFF_TOPE);
  float* topw    = (float*)(ws + OFF_TOPW);
  int*   counts  = (int*)(ws + OFF_CNT);
  int*   cursors = (int*)(ws + OFF_CUR);
  int*   offs    = (int*)(ws + OFF_OFFS);
  int*   sidx    = (int*)(ws + OFF_SIDX);
  int*   list128 = (int*)(ws + OFF_L128);
  int*   list64  = (int*)(ws + OFF_L64);

  hipMemsetAsync(ws + OFF_CNT, 0, 2048 + 128, stream);

  k_pre<<<5120, 256, 0, stream>>>(x, rw, gw, uw, dw, xbf, tope, topw, gws, uws, dws);
  k_hist<<<T_TOK * 2 / 256, 256, 0, stream>>>(tope, counts);
  k_offsets<<<1, 64, 0, stream>>>(counts, offs, list128, list64);
  k_scatter<<<T_TOK / 256, 256, 0, stream>>>(tope, topw, offs, cursors, stok, swt, sidx);
  k_gateup<<<dim3(8, 160), 256, 0, stream>>>(
      xbf, gws, uws, stok, counts, offs, list128, hid);
  k_down<<<dim3(2, 288), 256, 0, stream>>>(
      hid, dws, counts, offs, list64, ybuf);
  k_gather<<<T_TOK / 4, 256, 0, stream>>>(ybuf, sidx, topw, out);
}